// Round 22
// baseline (204.901 us; speedup 1.0000x reference)
//
#include <hip/hip_runtime.h>

typedef short bf8_t __attribute__((ext_vector_type(8)));   // 8 bf16 in 4 VGPRs
typedef float f32x4 __attribute__((ext_vector_type(4)));
typedef unsigned short u16;

__device__ inline u16 f2bf(float f) {        // RNE f32 -> bf16
    unsigned u = __float_as_uint(f);
    return (u16)((u + 0x7fff + ((u >> 16) & 1)) >> 16);
}

// ---------------- Atomic-free CSR build (two-level LDS bucket sort) ----------------
// Buckets = dst>>8 (<=256 buckets for N<=65536). All atomics are LDS-scope.
#define EBLK 2048

// k1: per-block bucket histogram + per-edge local rank (LDS atomics only).
__global__ __launch_bounds__(256) void bkt_hist(
        const int* __restrict__ dst, int* __restrict__ bcnt,
        u16* __restrict__ lrank1, int E) {
    __shared__ int bins[256];
    int tid = threadIdx.x;
    bins[tid] = 0;
    __syncthreads();
    int base = blockIdx.x * EBLK;
    int end = min(base + EBLK, E);
    for (int e = base + tid; e < end; e += 256) {
        int b = dst[e] >> 8;
        lrank1[e] = (u16)atomicAdd(&bins[b], 1);
    }
    __syncthreads();
    bcnt[blockIdx.x * 256 + tid] = bins[tid];
}

// k2: per-bucket exclusive prefix over edge-blocks + bucket bases. One block.
__global__ __launch_bounds__(256) void bkt_prefix(
        int* __restrict__ bcnt, int* __restrict__ bbase, int nebk) {
    int b = threadIdx.x;
    int run = 0;
#pragma unroll 4
    for (int k = 0; k < nebk; ++k) {
        int t = bcnt[k * 256 + b];
        bcnt[k * 256 + b] = run;
        run += t;
    }
    __shared__ int tot[256];
    tot[b] = run;
    __syncthreads();
    if (b == 0) {
        int r = 0;
        for (int k = 0; k < 256; ++k) { bbase[k] = r; r += tot[k]; }
        bbase[256] = r;
    }
}

// k3: scatter edges into bucket-sorted ebuf (packed src | dlow<<16).
__global__ __launch_bounds__(256) void bkt_scatter(
        const int* __restrict__ src, const int* __restrict__ dst,
        const u16* __restrict__ lrank1, const int* __restrict__ bcnt,
        const int* __restrict__ bbase, unsigned* __restrict__ ebuf, int E) {
    int base = blockIdx.x * EBLK;
    int end = min(base + EBLK, E);
    for (int e = base + threadIdx.x; e < end; e += 256) {
        int d = dst[e];
        int b = d >> 8;
        int pos = bbase[b] + bcnt[blockIdx.x * 256 + b] + (int)lrank1[e];
        unsigned v = (unsigned)src[e] | ((unsigned)(d & 255) << 16);
        __builtin_nontemporal_store(v, &ebuf[pos]);
    }
}

// k4: per-bucket node histogram (deg) + per-edge rank within node. Replaces the
// 800k device-scope atomics (42.6us: memory-side RMW throughput wall) with LDS.
__global__ __launch_bounds__(256) void bkt_nodehist(
        const unsigned* __restrict__ ebuf, const int* __restrict__ bbase,
        int* __restrict__ deg, u16* __restrict__ lrank2, int n) {
    __shared__ int hist[256];
    int tid = threadIdx.x;
    hist[tid] = 0;
    __syncthreads();
    int b = blockIdx.x;
    int s0 = bbase[b], s1 = bbase[b + 1];
    for (int i = s0 + tid; i < s1; i += 256) {
        unsigned u = ebuf[i];
        lrank2[i] = (u16)atomicAdd(&hist[u >> 16], 1);
    }
    __syncthreads();
    int node = b * 256 + tid;
    if (node < n) deg[node] = hist[tid];    // covers every node: no memset needed
}

// k5 (after row_ptr scan): fill padded CSR; bucket-local u16 scatter (L2-friendly).
__global__ __launch_bounds__(256) void bkt_fill(
        const unsigned* __restrict__ ebuf, const int* __restrict__ bbase,
        const u16* __restrict__ lrank2, const int* __restrict__ row_ptr,
        u16* __restrict__ csr_src, int n) {
    int b = blockIdx.x;
    int s0 = bbase[b], s1 = bbase[b + 1];
    for (int i = s0 + threadIdx.x; i < s1; i += 256) {
        unsigned u = ebuf[i];
        int node = b * 256 + (int)(u >> 16);
        int pos = row_ptr[node] + 1 + (int)lrank2[i];
        __builtin_nontemporal_store((u16)(u & 0xffffu), &csr_src[pos]);
    }
}

// ---------------- Scans (padded list length = (deg+1) rounded up to 8) ----------------

__global__ void scan_blocksum(const int* __restrict__ deg, int* __restrict__ bsum,
                              float* __restrict__ dinv, int n) {
    int i = blockIdx.x * 256 + threadIdx.x;
    int d = (i < n) ? (deg[i] + 1) : 0;
    if (i < n) dinv[i] = rsqrtf((float)d);
    int v = (i < n) ? ((d + 7) & ~7) : 0;
    for (int off = 32; off > 0; off >>= 1) v += __shfl_down(v, off, 64);
    __shared__ int ws[4];
    if ((threadIdx.x & 63) == 0) ws[threadIdx.x >> 6] = v;
    __syncthreads();
    if (threadIdx.x == 0) bsum[blockIdx.x] = ws[0] + ws[1] + ws[2] + ws[3];
}

__global__ void scan_offsets(const int* __restrict__ bsum, int* __restrict__ boff, int nblk) {
    __shared__ int buf[256];
    int tid = threadIdx.x;
    int v = (tid < nblk) ? bsum[tid] : 0;
    buf[tid] = v;
    __syncthreads();
    for (int off = 1; off < 256; off <<= 1) {
        int t = (tid >= off) ? buf[tid - off] : 0;
        __syncthreads();
        buf[tid] += t;
        __syncthreads();
    }
    if (tid < nblk) boff[tid] = buf[tid] - v;   // exclusive
}

__global__ void scan_rowptr(const int* __restrict__ deg, const int* __restrict__ boff,
                            int* __restrict__ row_ptr, int n) {
    __shared__ int buf[256];
    int tid = threadIdx.x;
    int i = blockIdx.x * 256 + tid;
    int v = (i < n) ? ((deg[i] + 8) & ~7) : 0;   // (deg+1 + 7) & ~7
    buf[tid] = v;
    __syncthreads();
    for (int off = 1; off < 256; off <<= 1) {
        int t = (tid >= off) ? buf[tid - off] : 0;
        __syncthreads();
        buf[tid] += t;
        __syncthreads();
    }
    int excl = buf[tid] - v + boff[blockIdx.x];
    if (i < n) row_ptr[i] = excl;
    if (i == n - 1) row_ptr[n] = excl + v;
}

// ---------------- Fused prep: self-loops+pads + x prescale + W^T + W3@Wh fold ------
// Pads point to row N (a zero row) -> exact +0.0 in the gather sum.
// Layer-3 fold: out = pool(A h2) @ (W3 Wh) + (b3 Wh + bh)  (no ReLU on layer 3).

__global__ void prep_kernel(const int* __restrict__ row_ptr, const int* __restrict__ deg,
                            u16* __restrict__ csr_src,
                            const float* __restrict__ x, const float* __restrict__ dinv,
                            unsigned* __restrict__ x16, unsigned* __restrict__ h16a,
                            unsigned* __restrict__ h16b,
                            const float* __restrict__ W1, const float* __restrict__ W2,
                            const float* __restrict__ W3,
                            const float* __restrict__ Wh, const float* __restrict__ b3,
                            const float* __restrict__ bh,
                            u16* __restrict__ Wt1, u16* __restrict__ Wt2,
                            float* __restrict__ WhF, float* __restrict__ bhF,
                            int n, int total8) {
    int gid = blockIdx.x * 256 + threadIdx.x;
    if (gid < n) {                           // self-loop at slot 0 + pad fill -> zero row n
        int s = gid;
        int beg = row_ptr[s];
        csr_src[beg] = (u16)s;
        int fill0 = beg + deg[s] + 1, fill1 = row_ptr[s + 1];
        for (int p = fill0; p < fill1; ++p) csr_src[p] = (u16)n;
        return;
    }
    int i = gid - n;
    if (i < total8) {                        // x2bf: 8 elems/thread, prescaled by dinv
        float dn = dinv[i >> 3];
        const float4* x4 = (const float4*)x;
        float4 a = x4[i * 2], b = x4[i * 2 + 1];
        uint4 o;
        o.x = (unsigned)f2bf(a.x * dn) | ((unsigned)f2bf(a.y * dn) << 16);
        o.y = (unsigned)f2bf(a.z * dn) | ((unsigned)f2bf(a.w * dn) << 16);
        o.z = (unsigned)f2bf(b.x * dn) | ((unsigned)f2bf(b.y * dn) << 16);
        o.w = (unsigned)f2bf(b.z * dn) | ((unsigned)f2bf(b.w * dn) << 16);
        ((uint4*)x16)[i] = o;
        return;
    }
    int j = i - total8;
    if (j < 8192) {                          // W1^T bf16: K=64
        int nn = j / 64, k = j - nn * 64;
        Wt1[j] = f2bf(W1[k * 128 + nn]);
        return;
    }
    if (j < 24576) {                         // W2^T bf16: K=128
        int jj = j - 8192;
        int nn = jj / 128, k = jj - nn * 128;
        Wt2[jj] = f2bf(W2[k * 128 + nn]);
        return;
    }
    if (j < 25600) {                         // WhF = W3 @ Wh  [128 x 8], fp32
        int jj = j - 24576;
        int k = jj >> 3, o = jj & 7;
        float a = 0.f;
        for (int q = 0; q < 128; ++q)
            a += W3[k * 128 + q] * Wh[q * 8 + o];
        WhF[jj] = a;
        return;
    }
    if (j < 25608) {                         // bhF = b3 @ Wh + bh  [8]
        int o = j - 25600;
        float a = bh[o];
        for (int q = 0; q < 128; ++q)
            a += b3[q] * Wh[q * 8 + o];
        bhF[o] = a;
        return;
    }
    int z = j - 25608;                       // zero rows (row n of x16 / h16a / h16b)
    if (z < 8)       ((uint4*)x16) [(size_t)n * 8  + z]        = make_uint4(0, 0, 0, 0);
    else if (z < 24) ((uint4*)h16a)[(size_t)n * 16 + (z - 8)]  = make_uint4(0, 0, 0, 0);
    else if (z < 40) ((uint4*)h16b)[(size_t)n * 16 + (z - 24)] = make_uint4(0, 0, 0, 0);
}

// ---------------- Gather helpers ----------------

__device__ inline void bf8_add(uint4 a, float* acc) {
#pragma unroll
    for (int j = 0; j < 4; ++j) {
        unsigned u = ((const unsigned*)&a)[j];
        acc[2 * j]     += __uint_as_float(u << 16);
        acc[2 * j + 1] += __uint_as_float(u & 0xffff0000u);
    }
}

__device__ inline uint4 pack_bf8(const float* v, float dn) {
    uint4 o;
    o.x = (unsigned)f2bf(v[0] * dn) | ((unsigned)f2bf(v[1] * dn) << 16);
    o.y = (unsigned)f2bf(v[2] * dn) | ((unsigned)f2bf(v[3] * dn) << 16);
    o.z = (unsigned)f2bf(v[4] * dn) | ((unsigned)f2bf(v[5] * dn) << 16);
    o.w = (unsigned)f2bf(v[6] * dn) | ((unsigned)f2bf(v[7] * dn) << 16);
    return o;
}

// ---------------- Fused aggregate + MFMA GEMM (layers 1,2) ----------------
// Lists padded to x8, 16B-aligned: one uint4 idx load = 8 u16 indices; the 8 row
// loads are INDEPENDENT. Pads hit the L1-resident zero row. Plain row loads
// (R16: nt-loads cost +40% — L2 reuse is the lifeline).

template<int K, bool RELU, bool BF16OUT>
__global__ __launch_bounds__(256) void agg_gemm(
        const u16* __restrict__ in, const u16* __restrict__ Wt16,
        const float* __restrict__ bias, void* __restrict__ outp,
        const int* __restrict__ row_ptr, const u16* __restrict__ csr_src,
        const float* __restrict__ dinv, int n) {
    constexpr int KS = K / 32;
    __shared__ u16 As[16 * K];
    int w = threadIdx.x >> 6, lane = threadIdx.x & 63;
    int base = blockIdx.x * 16;
    int lr = lane & 15, lk = lane >> 4;

    bf8_t B[2][KS];
#pragma unroll
    for (int f = 0; f < 2; ++f) {
        int col = w * 32 + f * 16 + lr;
#pragma unroll
        for (int ks = 0; ks < KS; ++ks)
            B[f][ks] = *reinterpret_cast<const bf8_t*>(&Wt16[(size_t)col * K + ks * 32 + lk * 8]);
    }

    const uint4* in4 = (const uint4*)in;
    int g = lane >> 4;
    int row = w * 4 + g;
    int node = base + row;
    float acc[8] = {0.f, 0.f, 0.f, 0.f, 0.f, 0.f, 0.f, 0.f};

    if (K == 128) {
        int col = lane & 15;
        if (node < n) {
            int beg = row_ptr[node];
            int niter = (row_ptr[node + 1] - beg) >> 3;
            const uint4* idxp = (const uint4*)(csr_src + beg);
            uint4 iv = idxp[0];
            for (int it = 0; it < niter; ++it) {
                uint4 ivn = idxp[it + 1];                        // slack-padded overread
                int s0 = iv.x & 0xffff, s1 = iv.x >> 16;
                int s2 = iv.y & 0xffff, s3 = iv.y >> 16;
                int s4 = iv.z & 0xffff, s5 = iv.z >> 16;
                int s6 = iv.w & 0xffff, s7 = iv.w >> 16;
                uint4 a0 = in4[(size_t)s0 * 16 + col];
                uint4 a1 = in4[(size_t)s1 * 16 + col];
                uint4 a2 = in4[(size_t)s2 * 16 + col];
                uint4 a3 = in4[(size_t)s3 * 16 + col];
                bf8_add(a0, acc); bf8_add(a1, acc);
                bf8_add(a2, acc); bf8_add(a3, acc);
                uint4 a4 = in4[(size_t)s4 * 16 + col];
                uint4 a5 = in4[(size_t)s5 * 16 + col];
                uint4 a6 = in4[(size_t)s6 * 16 + col];
                uint4 a7 = in4[(size_t)s7 * 16 + col];
                bf8_add(a4, acc); bf8_add(a5, acc);
                bf8_add(a6, acc); bf8_add(a7, acc);
                iv = ivn;
            }
        }
        float dn = (node < n) ? dinv[node] : 0.f;
        int off = row * K + ((col * 8) ^ ((row & 7) << 3));
        *(uint4*)&As[off] = pack_bf8(acc, dn);
    } else {
        int sub = (lane >> 3) & 1;
        int col = lane & 7;
        if (node < n) {
            int beg = row_ptr[node];
            int niter = (row_ptr[node + 1] - beg) >> 3;
            const uint4* idxp = (const uint4*)(csr_src + beg);
            uint4 iv = idxp[0];
            for (int it = 0; it < niter; ++it) {
                uint4 ivn = idxp[it + 1];
                int e0 = sub ? (int)(iv.x >> 16) : (int)(iv.x & 0xffff);
                int e1 = sub ? (int)(iv.y >> 16) : (int)(iv.y & 0xffff);
                int e2 = sub ? (int)(iv.z >> 16) : (int)(iv.z & 0xffff);
                int e3 = sub ? (int)(iv.w >> 16) : (int)(iv.w & 0xffff);
                uint4 a0 = in4[(size_t)e0 * 8 + col];
                uint4 a1 = in4[(size_t)e1 * 8 + col];
                uint4 a2 = in4[(size_t)e2 * 8 + col];
                uint4 a3 = in4[(size_t)e3 * 8 + col];
                bf8_add(a0, acc); bf8_add(a1, acc);
                bf8_add(a2, acc); bf8_add(a3, acc);
                iv = ivn;
            }
        }
#pragma unroll
        for (int j = 0; j < 8; ++j)
            acc[j] += __shfl_xor(acc[j], 8, 64);
        if (sub == 0) {
            float dn = (node < n) ? dinv[node] : 0.f;
            int off = row * K + ((col * 8) ^ ((row & 7) << 3));
            *(uint4*)&As[off] = pack_bf8(acc, dn);
        }
    }
    __syncthreads();

    f32x4 pacc[2] = {};
#pragma unroll
    for (int ks = 0; ks < KS; ++ks) {
        int off = lr * K + (((ks * 32) + lk * 8) ^ ((lr & 7) << 3));
        bf8_t a = *reinterpret_cast<const bf8_t*>(&As[off]);
#pragma unroll
        for (int f = 0; f < 2; ++f)
            pacc[f] = __builtin_amdgcn_mfma_f32_16x16x32_bf16(B[f][ks], a, pacc[f], 0, 0, 0);
    }

    int orow = base + lr;
    if (orow < n) {
        float dnx = BF16OUT ? dinv[orow] : 1.f;   // pre-scale next layer's gather operand
#pragma unroll
        for (int f = 0; f < 2; ++f) {
            int c0 = w * 32 + f * 16 + lk * 4;
            float4 bv = *(const float4*)&bias[c0];
            float v0 = pacc[f][0] + bv.x, v1 = pacc[f][1] + bv.y;
            float v2 = pacc[f][2] + bv.z, v3 = pacc[f][3] + bv.w;
            if (RELU) {
                v0 = fmaxf(v0, 0.f); v1 = fmaxf(v1, 0.f);
                v2 = fmaxf(v2, 0.f); v3 = fmaxf(v3, 0.f);
            }
            if (BF16OUT) {
                uint2 o;
                o.x = (unsigned)f2bf(v0 * dnx) | ((unsigned)f2bf(v1 * dnx) << 16);
                o.y = (unsigned)f2bf(v2 * dnx) | ((unsigned)f2bf(v3 * dnx) << 16);
                *(uint2*)&((u16*)outp)[(size_t)orow * 128 + c0] = o;
            } else {
                *(float4*)&((float*)outp)[(size_t)orow * 128 + c0] = make_float4(v0, v1, v2, v3);
            }
        }
    }
}

// ---------------- Layer 3: pure gather (GEMM folded into head) ----------------
// v[n] = dinv[n] * sum_s (dinv[s]*h2[s])  ->  bf16. No LDS, no barrier, no W.

__global__ __launch_bounds__(256) void agg_only(
        const u16* __restrict__ in, u16* __restrict__ out,
        const int* __restrict__ row_ptr, const u16* __restrict__ csr_src,
        const float* __restrict__ dinv, int n) {
    int lane = threadIdx.x & 63;
    int w = threadIdx.x >> 6;
    int node = blockIdx.x * 16 + w * 4 + (lane >> 4);
    int col = lane & 15;
    if (node >= n) return;
    const uint4* in4 = (const uint4*)in;
    float acc[8] = {0.f, 0.f, 0.f, 0.f, 0.f, 0.f, 0.f, 0.f};
    int beg = row_ptr[node];
    int niter = (row_ptr[node + 1] - beg) >> 3;
    const uint4* idxp = (const uint4*)(csr_src + beg);
    uint4 iv = idxp[0];
    for (int it = 0; it < niter; ++it) {
        uint4 ivn = idxp[it + 1];
        int s0 = iv.x & 0xffff, s1 = iv.x >> 16;
        int s2 = iv.y & 0xffff, s3 = iv.y >> 16;
        int s4 = iv.z & 0xffff, s5 = iv.z >> 16;
        int s6 = iv.w & 0xffff, s7 = iv.w >> 16;
        uint4 a0 = in4[(size_t)s0 * 16 + col];
        uint4 a1 = in4[(size_t)s1 * 16 + col];
        uint4 a2 = in4[(size_t)s2 * 16 + col];
        uint4 a3 = in4[(size_t)s3 * 16 + col];
        bf8_add(a0, acc); bf8_add(a1, acc);
        bf8_add(a2, acc); bf8_add(a3, acc);
        uint4 a4 = in4[(size_t)s4 * 16 + col];
        uint4 a5 = in4[(size_t)s5 * 16 + col];
        uint4 a6 = in4[(size_t)s6 * 16 + col];
        uint4 a7 = in4[(size_t)s7 * 16 + col];
        bf8_add(a4, acc); bf8_add(a5, acc);
        bf8_add(a6, acc); bf8_add(a7, acc);
        iv = ivn;
    }
    ((uint4*)out)[(size_t)node * 16 + col] = pack_bf8(acc, dinv[node]);
}

// ---------------- Pooling + folded head ----------------
// batch sorted -> per-graph contiguous row range via binary search.

__device__ inline int lbound(const int* __restrict__ batch, int n, int g) {
    int lo = 0, hi = n;
    while (lo < hi) {
        int mid = (lo + hi) >> 1;
        if (batch[mid] < g) lo = mid + 1; else hi = mid;
    }
    return lo;
}

#define PSPLIT 16
__global__ __launch_bounds__(256) void pool_part(
        const u16* __restrict__ v, const int* __restrict__ batch,
        float* __restrict__ part, int n) {
    int g = blockIdx.x >> 4, sp = blockIdx.x & (PSPLIT - 1);
    int tid = threadIdx.x;
    int c2 = tid & 63;          // u32 col (2 bf16)
    int rs = tid >> 6;          // 4-way row split
    int beg = lbound(batch, n, g), end = lbound(batch, n, g + 1);
    int len = end - beg;
    int chunk = (len + PSPLIT - 1) >> 4;
    int r0 = beg + sp * chunk;
    int r1 = min(r0 + chunk, end);
    const unsigned* v32 = (const unsigned*)v;   // row = 64 u32
    float ax = 0.f, ay = 0.f;
    for (int r = r0 + rs; r < r1; r += 4) {
        unsigned u = v32[(size_t)r * 64 + c2];
        ax += __uint_as_float(u << 16);
        ay += __uint_as_float(u & 0xffff0000u);
    }
    __shared__ float bufx[256], bufy[256];
    bufx[tid] = ax; bufy[tid] = ay;
    __syncthreads();
    if (rs == 0) {
        float sx = bufx[c2] + bufx[c2 + 64] + bufx[c2 + 128] + bufx[c2 + 192];
        float sy = bufy[c2] + bufy[c2 + 64] + bufy[c2 + 128] + bufy[c2 + 192];
        part[(size_t)blockIdx.x * 128 + c2 * 2]     = sx;
        part[(size_t)blockIdx.x * 128 + c2 * 2 + 1] = sy;
    }
}

// Fused: reduce 16 partials -> mean row -> folded head (W3@Wh [128x8], b3@Wh+bh).
__global__ __launch_bounds__(128) void pool_head(
        const float* __restrict__ part, const int* __restrict__ batch,
        const float* __restrict__ WhF, const float* __restrict__ bhF,
        float* __restrict__ out, int n) {
    int g = blockIdx.x;
    int tid = threadIdx.x;
    float acc = 0.f;
#pragma unroll
    for (int sp = 0; sp < PSPLIT; ++sp)
        acc += part[((size_t)g * PSPLIT + sp) * 128 + tid];
    int cnt = lbound(batch, n, g + 1) - lbound(batch, n, g);
    __shared__ float grow[128];
    grow[tid] = acc / fmaxf((float)cnt, 1.f);
    __syncthreads();
    int sub = tid >> 3, o = tid & 7;
    float p = 0.f;
    for (int k = sub; k < 128; k += 16)
        p += grow[k] * WhF[k * 8 + o];
    __shared__ float p2[128];
    p2[tid] = p;
    __syncthreads();
    for (int s = 8; s > 0; s >>= 1) {
        if (sub < s) p2[sub * 8 + o] += p2[(sub + s) * 8 + o];
        __syncthreads();
    }
    if (tid < 8) out[g * 8 + tid] = p2[tid] + bhF[tid];
}

// ---------------- Launch ----------------

extern "C" void kernel_launch(void* const* d_in, const int* in_sizes, int n_in,
                              void* d_out, int out_size, void* d_ws, size_t ws_size,
                              hipStream_t stream) {
    const float* x  = (const float*)d_in[0];
    const float* W1 = (const float*)d_in[1];
    const float* b1 = (const float*)d_in[2];
    const float* W2 = (const float*)d_in[3];
    const float* b2 = (const float*)d_in[4];
    const float* W3 = (const float*)d_in[5];
    const float* b3 = (const float*)d_in[6];
    const float* Wh = (const float*)d_in[7];
    const float* bh = (const float*)d_in[8];
    const int* edge_index = (const int*)d_in[9];
    const int* batch = (const int*)d_in[10];
    (void)n_in; (void)ws_size;

    const int N = in_sizes[10];
    const int E = in_sizes[9] / 2;
    const int G = out_size / 8;
    const int* esrc = edge_index;
    const int* edst = edge_index + E;

    size_t off = 0;
    auto take = [&](size_t bytes) {
        void* p = (char*)d_ws + off;
        off += (bytes + 255) & ~(size_t)255;
        return p;
    };
    int nebk = (E + EBLK - 1) / EBLK;          // edge blocks for bucket passes
    int NB   = (N + 255) >> 8;                  // level-1 buckets (== nblk)
    int*   deg      = (int*)take((size_t)N * 4);
    float* dinv     = (float*)take((size_t)N * 4);
    int*   row_ptr  = (int*)take((size_t)(N + 1) * 4);
    u16*   lrank1   = (u16*)take((size_t)E * 2);
    u16*   lrank2   = (u16*)take((size_t)E * 2);
    unsigned* ebuf  = (unsigned*)take((size_t)E * 4);
    int*   bcnt     = (int*)take((size_t)nebk * 256 * 4);
    int*   bbase    = (int*)take(257 * 4);
    u16*   csr_src  = (u16*)take(((size_t)E + 8 * (size_t)N + 16) * 2);  // padded lists + slack
    int*   bsum     = (int*)take(256 * 4);
    int*   boff     = (int*)take(256 * 4);
    float* part     = (float*)take((size_t)G * PSPLIT * 128 * 4);
    u16*   x16      = (u16*)take((size_t)(N + 1) * 64 * 2);    // +1: zero row
    u16*   h16a     = (u16*)take((size_t)(N + 1) * 128 * 2);   // +1: zero row
    u16*   h16b     = (u16*)take((size_t)(N + 1) * 128 * 2);   // +1: zero row
    u16*   vbuf     = (u16*)take((size_t)N * 128 * 2);         // layer-3 agg output
    u16*   Wt1      = (u16*)take((size_t)128 * 64 * 2);
    u16*   Wt2      = (u16*)take((size_t)128 * 128 * 2);
    float* WhF      = (float*)take((size_t)128 * 8 * 4);       // W3 @ Wh
    float* bhF      = (float*)take(8 * 4);                     // b3 @ Wh + bh

    int nblk  = (N + 255) / 256;
    int fgrid = (N + 15) / 16;
    int total8 = N * 64 / 8;
    int prep_threads = N + total8 + 25608 + 40;

    // CSR build: two-level LDS bucket sort (zero global atomics)
    bkt_hist<<<nebk, 256, 0, stream>>>(edst, bcnt, lrank1, E);
    bkt_prefix<<<1, 256, 0, stream>>>(bcnt, bbase, nebk);
    bkt_scatter<<<nebk, 256, 0, stream>>>(esrc, edst, lrank1, bcnt, bbase, ebuf, E);
    bkt_nodehist<<<NB, 256, 0, stream>>>(ebuf, bbase, deg, lrank2, N);
    scan_blocksum<<<nblk, 256, 0, stream>>>(deg, bsum, dinv, N);
    scan_offsets<<<1, 256, 0, stream>>>(bsum, boff, nblk);
    scan_rowptr<<<nblk, 256, 0, stream>>>(deg, boff, row_ptr, N);
    bkt_fill<<<NB, 256, 0, stream>>>(ebuf, bbase, lrank2, row_ptr, csr_src, N);
    prep_kernel<<<(prep_threads + 255) / 256, 256, 0, stream>>>(
        row_ptr, deg, csr_src, x, dinv,
        (unsigned*)x16, (unsigned*)h16a, (unsigned*)h16b,
        W1, W2, W3, Wh, b3, bh, Wt1, Wt2, WhF, bhF, N, total8);

    // Layers 1,2 fused agg+GEMM (Agg(x)@W == Agg(x@W) at layer 1); layer 3 = pure gather
    agg_gemm<64,  true, true><<<fgrid, 256, 0, stream>>>(x16,  Wt1, b1, h16a, row_ptr, csr_src, dinv, N);
    agg_gemm<128, true, true><<<fgrid, 256, 0, stream>>>(h16a, Wt2, b2, h16b, row_ptr, csr_src, dinv, N);
    agg_only<<<fgrid, 256, 0, stream>>>(h16b, vbuf, row_ptr, csr_src, dinv, N);

    // Pool (binary-searched ranges) + folded head
    pool_part<<<G * PSPLIT, 256, 0, stream>>>(vbuf, batch, part, N);
    pool_head<<<G, 128, 0, stream>>>(part, batch, WhF, bhF, (float*)d_out, N);
}

// Round 23
// 188.332 us; speedup vs baseline: 1.0880x; 1.0880x over previous
//
#include <hip/hip_runtime.h>

typedef short bf8_t __attribute__((ext_vector_type(8)));   // 8 bf16 in 4 VGPRs
typedef float f32x4 __attribute__((ext_vector_type(4)));
typedef unsigned short u16;

__device__ inline u16 f2bf(float f) {        // RNE f32 -> bf16
    unsigned u = __float_as_uint(f);
    return (u16)((u + 0x7fff + ((u >> 16) & 1)) >> 16);
}

// ---------------- CSR construction (lists padded to x8 for vector idx loads) -------

// 8 edges/thread, batched: 4 coalesced int2 loads -> 8 independent atomics in
// flight -> 8 rank stores. R20 profile: 1-2 edge/thread version ran at ~8%
// occupancy (waves exit after one atomic round-trip); batching raises per-wave
// in-flight atomics and wave lifetime.
__global__ __launch_bounds__(256) void deg_kernel(
        const int* __restrict__ dst, int* __restrict__ deg,
        u16* __restrict__ rank, int E) {
    int tid = threadIdx.x;
    int base = blockIdx.x * 2048 + tid * 2;
    int2 d0, d1, d2, d3;
    int e0 = base, e1 = base + 512, e2 = base + 1024, e3 = base + 1536;
    bool v0 = e0 < E, v1 = e1 < E, v2 = e2 < E, v3 = e3 < E;   // E even -> pair-safe
    if (v0) d0 = *(const int2*)&dst[e0];
    if (v1) d1 = *(const int2*)&dst[e1];
    if (v2) d2 = *(const int2*)&dst[e2];
    if (v3) d3 = *(const int2*)&dst[e3];
    u16 r0a, r0b, r1a, r1b, r2a, r2b, r3a, r3b;
    if (v0) { r0a = (u16)atomicAdd(&deg[d0.x], 1); r0b = (u16)atomicAdd(&deg[d0.y], 1); }
    if (v1) { r1a = (u16)atomicAdd(&deg[d1.x], 1); r1b = (u16)atomicAdd(&deg[d1.y], 1); }
    if (v2) { r2a = (u16)atomicAdd(&deg[d2.x], 1); r2b = (u16)atomicAdd(&deg[d2.y], 1); }
    if (v3) { r3a = (u16)atomicAdd(&deg[d3.x], 1); r3b = (u16)atomicAdd(&deg[d3.y], 1); }
    if (v0) { rank[e0] = r0a; rank[e0 + 1] = r0b; }
    if (v1) { rank[e1] = r1a; rank[e1 + 1] = r1b; }
    if (v2) { rank[e2] = r2a; rank[e2 + 1] = r2b; }
    if (v3) { rank[e3] = r3a; rank[e3 + 1] = r3b; }
}

// block sums of PADDED list length ((deg+1) rounded up to 8); also dinv = rsqrt(deg+1)
__global__ void scan_blocksum(const int* __restrict__ deg, int* __restrict__ bsum,
                              float* __restrict__ dinv, int n) {
    int i = blockIdx.x * 256 + threadIdx.x;
    int d = (i < n) ? (deg[i] + 1) : 0;
    if (i < n) dinv[i] = rsqrtf((float)d);
    int v = (i < n) ? ((d + 7) & ~7) : 0;
    for (int off = 32; off > 0; off >>= 1) v += __shfl_down(v, off, 64);
    __shared__ int ws[4];
    if ((threadIdx.x & 63) == 0) ws[threadIdx.x >> 6] = v;
    __syncthreads();
    if (threadIdx.x == 0) bsum[blockIdx.x] = ws[0] + ws[1] + ws[2] + ws[3];
}

__global__ void scan_offsets(const int* __restrict__ bsum, int* __restrict__ boff, int nblk) {
    __shared__ int buf[256];
    int tid = threadIdx.x;
    int v = (tid < nblk) ? bsum[tid] : 0;
    buf[tid] = v;
    __syncthreads();
    for (int off = 1; off < 256; off <<= 1) {
        int t = (tid >= off) ? buf[tid - off] : 0;
        __syncthreads();
        buf[tid] += t;
        __syncthreads();
    }
    if (tid < nblk) boff[tid] = buf[tid] - v;   // exclusive
}

__global__ void scan_rowptr(const int* __restrict__ deg, const int* __restrict__ boff,
                            int* __restrict__ row_ptr, int n) {
    __shared__ int buf[256];
    int tid = threadIdx.x;
    int i = blockIdx.x * 256 + tid;
    int v = (i < n) ? ((deg[i] + 8) & ~7) : 0;   // (deg+1 + 7) & ~7
    buf[tid] = v;
    __syncthreads();
    for (int off = 1; off < 256; off <<= 1) {
        int t = (tid >= off) ? buf[tid - off] : 0;
        __syncthreads();
        buf[tid] += t;
        __syncthreads();
    }
    int excl = buf[tid] - v + boff[blockIdx.x];
    if (i < n) row_ptr[i] = excl;
    if (i == n - 1) row_ptr[n] = excl + v;
}

// ---------------- Fused prep: fill + pads + x prescale + W^T + W3@Wh fold + zeros --
// Pads point to row N (a zero row) -> exact +0.0 in the gather sum.
// Layer-3 fold: out = pool(A h2) @ (W3 Wh) + (b3 Wh + bh)  (no ReLU on layer 3).

__global__ void prep_kernel(const int* __restrict__ src, const int* __restrict__ dst,
                            const u16* __restrict__ rank, const int* __restrict__ row_ptr,
                            const int* __restrict__ deg,
                            u16* __restrict__ csr_src,
                            const float* __restrict__ x, const float* __restrict__ dinv,
                            unsigned* __restrict__ x16, unsigned* __restrict__ h16a,
                            unsigned* __restrict__ h16b,
                            const float* __restrict__ W1, const float* __restrict__ W2,
                            const float* __restrict__ W3,
                            const float* __restrict__ Wh, const float* __restrict__ b3,
                            const float* __restrict__ bh,
                            u16* __restrict__ Wt1, u16* __restrict__ Wt2,
                            float* __restrict__ WhF, float* __restrict__ bhF,
                            int E, int n, int total8) {
    int gid = blockIdx.x * 256 + threadIdx.x;
    if (gid < E) {
        int s = src[gid], d = dst[gid];
        int pos = row_ptr[d] + 1 + (int)rank[gid];
        __builtin_nontemporal_store((u16)s, &csr_src[pos]);
        return;
    }
    if (gid < E + n) {                       // self-loop at slot 0 + pad fill -> zero row n
        int s = gid - E;
        int beg = row_ptr[s];
        csr_src[beg] = (u16)s;
        int fill0 = beg + deg[s] + 1, fill1 = row_ptr[s + 1];
        for (int p = fill0; p < fill1; ++p) csr_src[p] = (u16)n;
        return;
    }
    int i = gid - (E + n);
    if (i < total8) {                        // x2bf: 8 elems/thread, prescaled by dinv
        float dn = dinv[i >> 3];
        const float4* x4 = (const float4*)x;
        float4 a = x4[i * 2], b = x4[i * 2 + 1];
        uint4 o;
        o.x = (unsigned)f2bf(a.x * dn) | ((unsigned)f2bf(a.y * dn) << 16);
        o.y = (unsigned)f2bf(a.z * dn) | ((unsigned)f2bf(a.w * dn) << 16);
        o.z = (unsigned)f2bf(b.x * dn) | ((unsigned)f2bf(b.y * dn) << 16);
        o.w = (unsigned)f2bf(b.z * dn) | ((unsigned)f2bf(b.w * dn) << 16);
        ((uint4*)x16)[i] = o;
        return;
    }
    int j = i - total8;
    if (j < 8192) {                          // W1^T bf16: K=64
        int nn = j / 64, k = j - nn * 64;
        Wt1[j] = f2bf(W1[k * 128 + nn]);
        return;
    }
    if (j < 24576) {                         // W2^T bf16: K=128
        int jj = j - 8192;
        int nn = jj / 128, k = jj - nn * 128;
        Wt2[jj] = f2bf(W2[k * 128 + nn]);
        return;
    }
    if (j < 25600) {                         // WhF = W3 @ Wh  [128 x 8], fp32
        int jj = j - 24576;
        int k = jj >> 3, o = jj & 7;
        float a = 0.f;
        for (int q = 0; q < 128; ++q)
            a += W3[k * 128 + q] * Wh[q * 8 + o];
        WhF[jj] = a;
        return;
    }
    if (j < 25608) {                         // bhF = b3 @ Wh + bh  [8]
        int o = j - 25600;
        float a = bh[o];
        for (int q = 0; q < 128; ++q)
            a += b3[q] * Wh[q * 8 + o];
        bhF[o] = a;
        return;
    }
    int z = j - 25608;                       // zero rows (row n of x16 / h16a / h16b)
    if (z < 8)       ((uint4*)x16) [(size_t)n * 8  + z]        = make_uint4(0, 0, 0, 0);
    else if (z < 24) ((uint4*)h16a)[(size_t)n * 16 + (z - 8)]  = make_uint4(0, 0, 0, 0);
    else if (z < 40) ((uint4*)h16b)[(size_t)n * 16 + (z - 24)] = make_uint4(0, 0, 0, 0);
}

// ---------------- Gather helpers ----------------

__device__ inline void bf8_add(uint4 a, float* acc) {
#pragma unroll
    for (int j = 0; j < 4; ++j) {
        unsigned u = ((const unsigned*)&a)[j];
        acc[2 * j]     += __uint_as_float(u << 16);
        acc[2 * j + 1] += __uint_as_float(u & 0xffff0000u);
    }
}

__device__ inline uint4 pack_bf8(const float* v, float dn) {
    uint4 o;
    o.x = (unsigned)f2bf(v[0] * dn) | ((unsigned)f2bf(v[1] * dn) << 16);
    o.y = (unsigned)f2bf(v[2] * dn) | ((unsigned)f2bf(v[3] * dn) << 16);
    o.z = (unsigned)f2bf(v[4] * dn) | ((unsigned)f2bf(v[5] * dn) << 16);
    o.w = (unsigned)f2bf(v[6] * dn) | ((unsigned)f2bf(v[7] * dn) << 16);
    return o;
}

// ---------------- Fused aggregate + MFMA GEMM (layers 1,2) ----------------
// Lists padded to x8, 16B-aligned: one uint4 idx load = 8 u16 indices; the 8 row
// loads are INDEPENDENT. Pads hit the L1-resident zero row. Plain row loads
// (R16: nt-loads cost +40% — L2 reuse is the lifeline).

template<int K, bool RELU, bool BF16OUT>
__global__ __launch_bounds__(256) void agg_gemm(
        const u16* __restrict__ in, const u16* __restrict__ Wt16,
        const float* __restrict__ bias, void* __restrict__ outp,
        const int* __restrict__ row_ptr, const u16* __restrict__ csr_src,
        const float* __restrict__ dinv, int n) {
    constexpr int KS = K / 32;
    __shared__ u16 As[16 * K];
    int w = threadIdx.x >> 6, lane = threadIdx.x & 63;
    int base = blockIdx.x * 16;
    int lr = lane & 15, lk = lane >> 4;

    bf8_t B[2][KS];
#pragma unroll
    for (int f = 0; f < 2; ++f) {
        int col = w * 32 + f * 16 + lr;
#pragma unroll
        for (int ks = 0; ks < KS; ++ks)
            B[f][ks] = *reinterpret_cast<const bf8_t*>(&Wt16[(size_t)col * K + ks * 32 + lk * 8]);
    }

    const uint4* in4 = (const uint4*)in;
    int g = lane >> 4;
    int row = w * 4 + g;
    int node = base + row;
    float acc[8] = {0.f, 0.f, 0.f, 0.f, 0.f, 0.f, 0.f, 0.f};

    if (K == 128) {
        int col = lane & 15;
        if (node < n) {
            int beg = row_ptr[node];
            int niter = (row_ptr[node + 1] - beg) >> 3;
            const uint4* idxp = (const uint4*)(csr_src + beg);
            uint4 iv = idxp[0];
            for (int it = 0; it < niter; ++it) {
                uint4 ivn = idxp[it + 1];                        // slack-padded overread
                int s0 = iv.x & 0xffff, s1 = iv.x >> 16;
                int s2 = iv.y & 0xffff, s3 = iv.y >> 16;
                int s4 = iv.z & 0xffff, s5 = iv.z >> 16;
                int s6 = iv.w & 0xffff, s7 = iv.w >> 16;
                uint4 a0 = in4[(size_t)s0 * 16 + col];
                uint4 a1 = in4[(size_t)s1 * 16 + col];
                uint4 a2 = in4[(size_t)s2 * 16 + col];
                uint4 a3 = in4[(size_t)s3 * 16 + col];
                bf8_add(a0, acc); bf8_add(a1, acc);
                bf8_add(a2, acc); bf8_add(a3, acc);
                uint4 a4 = in4[(size_t)s4 * 16 + col];
                uint4 a5 = in4[(size_t)s5 * 16 + col];
                uint4 a6 = in4[(size_t)s6 * 16 + col];
                uint4 a7 = in4[(size_t)s7 * 16 + col];
                bf8_add(a4, acc); bf8_add(a5, acc);
                bf8_add(a6, acc); bf8_add(a7, acc);
                iv = ivn;
            }
        }
        float dn = (node < n) ? dinv[node] : 0.f;
        int off = row * K + ((col * 8) ^ ((row & 7) << 3));
        *(uint4*)&As[off] = pack_bf8(acc, dn);
    } else {
        int sub = (lane >> 3) & 1;
        int col = lane & 7;
        if (node < n) {
            int beg = row_ptr[node];
            int niter = (row_ptr[node + 1] - beg) >> 3;
            const uint4* idxp = (const uint4*)(csr_src + beg);
            uint4 iv = idxp[0];
            for (int it = 0; it < niter; ++it) {
                uint4 ivn = idxp[it + 1];
                int e0 = sub ? (int)(iv.x >> 16) : (int)(iv.x & 0xffff);
                int e1 = sub ? (int)(iv.y >> 16) : (int)(iv.y & 0xffff);
                int e2 = sub ? (int)(iv.z >> 16) : (int)(iv.z & 0xffff);
                int e3 = sub ? (int)(iv.w >> 16) : (int)(iv.w & 0xffff);
                uint4 a0 = in4[(size_t)e0 * 8 + col];
                uint4 a1 = in4[(size_t)e1 * 8 + col];
                uint4 a2 = in4[(size_t)e2 * 8 + col];
                uint4 a3 = in4[(size_t)e3 * 8 + col];
                bf8_add(a0, acc); bf8_add(a1, acc);
                bf8_add(a2, acc); bf8_add(a3, acc);
                iv = ivn;
            }
        }
#pragma unroll
        for (int j = 0; j < 8; ++j)
            acc[j] += __shfl_xor(acc[j], 8, 64);
        if (sub == 0) {
            float dn = (node < n) ? dinv[node] : 0.f;
            int off = row * K + ((col * 8) ^ ((row & 7) << 3));
            *(uint4*)&As[off] = pack_bf8(acc, dn);
        }
    }
    __syncthreads();

    f32x4 pacc[2] = {};
#pragma unroll
    for (int ks = 0; ks < KS; ++ks) {
        int off = lr * K + (((ks * 32) + lk * 8) ^ ((lr & 7) << 3));
        bf8_t a = *reinterpret_cast<const bf8_t*>(&As[off]);
#pragma unroll
        for (int f = 0; f < 2; ++f)
            pacc[f] = __builtin_amdgcn_mfma_f32_16x16x32_bf16(B[f][ks], a, pacc[f], 0, 0, 0);
    }

    int orow = base + lr;
    if (orow < n) {
        float dnx = BF16OUT ? dinv[orow] : 1.f;   // pre-scale next layer's gather operand
#pragma unroll
        for (int f = 0; f < 2; ++f) {
            int c0 = w * 32 + f * 16 + lk * 4;
            float4 bv = *(const float4*)&bias[c0];
            float v0 = pacc[f][0] + bv.x, v1 = pacc[f][1] + bv.y;
            float v2 = pacc[f][2] + bv.z, v3 = pacc[f][3] + bv.w;
            if (RELU) {
                v0 = fmaxf(v0, 0.f); v1 = fmaxf(v1, 0.f);
                v2 = fmaxf(v2, 0.f); v3 = fmaxf(v3, 0.f);
            }
            if (BF16OUT) {
                uint2 o;
                o.x = (unsigned)f2bf(v0 * dnx) | ((unsigned)f2bf(v1 * dnx) << 16);
                o.y = (unsigned)f2bf(v2 * dnx) | ((unsigned)f2bf(v3 * dnx) << 16);
                *(uint2*)&((u16*)outp)[(size_t)orow * 128 + c0] = o;
            } else {
                *(float4*)&((float*)outp)[(size_t)orow * 128 + c0] = make_float4(v0, v1, v2, v3);
            }
        }
    }
}

// ---------------- Layer 3: pure gather (GEMM folded into head) ----------------
// v[n] = dinv[n] * sum_s (dinv[s]*h2[s])  ->  bf16. No LDS, no barrier, no W.

__global__ __launch_bounds__(256) void agg_only(
        const u16* __restrict__ in, u16* __restrict__ out,
        const int* __restrict__ row_ptr, const u16* __restrict__ csr_src,
        const float* __restrict__ dinv, int n) {
    int lane = threadIdx.x & 63;
    int w = threadIdx.x >> 6;
    int node = blockIdx.x * 16 + w * 4 + (lane >> 4);
    int col = lane & 15;
    if (node >= n) return;
    const uint4* in4 = (const uint4*)in;
    float acc[8] = {0.f, 0.f, 0.f, 0.f, 0.f, 0.f, 0.f, 0.f};
    int beg = row_ptr[node];
    int niter = (row_ptr[node + 1] - beg) >> 3;
    const uint4* idxp = (const uint4*)(csr_src + beg);
    uint4 iv = idxp[0];
    for (int it = 0; it < niter; ++it) {
        uint4 ivn = idxp[it + 1];
        int s0 = iv.x & 0xffff, s1 = iv.x >> 16;
        int s2 = iv.y & 0xffff, s3 = iv.y >> 16;
        int s4 = iv.z & 0xffff, s5 = iv.z >> 16;
        int s6 = iv.w & 0xffff, s7 = iv.w >> 16;
        uint4 a0 = in4[(size_t)s0 * 16 + col];
        uint4 a1 = in4[(size_t)s1 * 16 + col];
        uint4 a2 = in4[(size_t)s2 * 16 + col];
        uint4 a3 = in4[(size_t)s3 * 16 + col];
        bf8_add(a0, acc); bf8_add(a1, acc);
        bf8_add(a2, acc); bf8_add(a3, acc);
        uint4 a4 = in4[(size_t)s4 * 16 + col];
        uint4 a5 = in4[(size_t)s5 * 16 + col];
        uint4 a6 = in4[(size_t)s6 * 16 + col];
        uint4 a7 = in4[(size_t)s7 * 16 + col];
        bf8_add(a4, acc); bf8_add(a5, acc);
        bf8_add(a6, acc); bf8_add(a7, acc);
        iv = ivn;
    }
    ((uint4*)out)[(size_t)node * 16 + col] = pack_bf8(acc, dinv[node]);
}

// ---------------- Pooling + folded head ----------------
// batch sorted -> per-graph contiguous row range via binary search.

__device__ inline int lbound(const int* __restrict__ batch, int n, int g) {
    int lo = 0, hi = n;
    while (lo < hi) {
        int mid = (lo + hi) >> 1;
        if (batch[mid] < g) lo = mid + 1; else hi = mid;
    }
    return lo;
}

#define PSPLIT 16
__global__ __launch_bounds__(256) void pool_part(
        const u16* __restrict__ v, const int* __restrict__ batch,
        float* __restrict__ part, int n) {
    int g = blockIdx.x >> 4, sp = blockIdx.x & (PSPLIT - 1);
    int tid = threadIdx.x;
    int c2 = tid & 63;          // u32 col (2 bf16)
    int rs = tid >> 6;          // 4-way row split
    int beg = lbound(batch, n, g), end = lbound(batch, n, g + 1);
    int len = end - beg;
    int chunk = (len + PSPLIT - 1) >> 4;
    int r0 = beg + sp * chunk;
    int r1 = min(r0 + chunk, end);
    const unsigned* v32 = (const unsigned*)v;   // row = 64 u32
    float ax = 0.f, ay = 0.f;
    for (int r = r0 + rs; r < r1; r += 4) {
        unsigned u = v32[(size_t)r * 64 + c2];
        ax += __uint_as_float(u << 16);
        ay += __uint_as_float(u & 0xffff0000u);
    }
    __shared__ float bufx[256], bufy[256];
    bufx[tid] = ax; bufy[tid] = ay;
    __syncthreads();
    if (rs == 0) {
        float sx = bufx[c2] + bufx[c2 + 64] + bufx[c2 + 128] + bufx[c2 + 192];
        float sy = bufy[c2] + bufy[c2 + 64] + bufy[c2 + 128] + bufy[c2 + 192];
        part[(size_t)blockIdx.x * 128 + c2 * 2]     = sx;
        part[(size_t)blockIdx.x * 128 + c2 * 2 + 1] = sy;
    }
}

// Fused: reduce 16 partials -> mean row -> folded head (W3@Wh [128x8], b3@Wh+bh).
__global__ __launch_bounds__(128) void pool_head(
        const float* __restrict__ part, const int* __restrict__ batch,
        const float* __restrict__ WhF, const float* __restrict__ bhF,
        float* __restrict__ out, int n) {
    int g = blockIdx.x;
    int tid = threadIdx.x;
    float acc = 0.f;
#pragma unroll
    for (int sp = 0; sp < PSPLIT; ++sp)
        acc += part[((size_t)g * PSPLIT + sp) * 128 + tid];
    int cnt = lbound(batch, n, g + 1) - lbound(batch, n, g);
    __shared__ float grow[128];
    grow[tid] = acc / fmaxf((float)cnt, 1.f);
    __syncthreads();
    int sub = tid >> 3, o = tid & 7;
    float p = 0.f;
    for (int k = sub; k < 128; k += 16)
        p += grow[k] * WhF[k * 8 + o];
    __shared__ float p2[128];
    p2[tid] = p;
    __syncthreads();
    for (int s = 8; s > 0; s >>= 1) {
        if (sub < s) p2[sub * 8 + o] += p2[(sub + s) * 8 + o];
        __syncthreads();
    }
    if (tid < 8) out[g * 8 + tid] = p2[tid] + bhF[tid];
}

// ---------------- Launch ----------------

extern "C" void kernel_launch(void* const* d_in, const int* in_sizes, int n_in,
                              void* d_out, int out_size, void* d_ws, size_t ws_size,
                              hipStream_t stream) {
    const float* x  = (const float*)d_in[0];
    const float* W1 = (const float*)d_in[1];
    const float* b1 = (const float*)d_in[2];
    const float* W2 = (const float*)d_in[3];
    const float* b2 = (const float*)d_in[4];
    const float* W3 = (const float*)d_in[5];
    const float* b3 = (const float*)d_in[6];
    const float* Wh = (const float*)d_in[7];
    const float* bh = (const float*)d_in[8];
    const int* edge_index = (const int*)d_in[9];
    const int* batch = (const int*)d_in[10];
    (void)n_in; (void)ws_size;

    const int N = in_sizes[10];
    const int E = in_sizes[9] / 2;
    const int G = out_size / 8;
    const int* esrc = edge_index;
    const int* edst = edge_index + E;

    size_t off = 0;
    auto take = [&](size_t bytes) {
        void* p = (char*)d_ws + off;
        off += (bytes + 255) & ~(size_t)255;
        return p;
    };
    int*   deg      = (int*)take((size_t)N * 4);
    float* dinv     = (float*)take((size_t)N * 4);
    int*   row_ptr  = (int*)take((size_t)(N + 1) * 4);
    u16*   rank     = (u16*)take((size_t)E * 2);
    u16*   csr_src  = (u16*)take(((size_t)E + 8 * (size_t)N + 16) * 2);  // padded lists + slack
    int*   bsum     = (int*)take(256 * 4);
    int*   boff     = (int*)take(256 * 4);
    float* part     = (float*)take((size_t)G * PSPLIT * 128 * 4);
    u16*   x16      = (u16*)take((size_t)(N + 1) * 64 * 2);    // +1: zero row
    u16*   h16a     = (u16*)take((size_t)(N + 1) * 128 * 2);   // +1: zero row
    u16*   h16b     = (u16*)take((size_t)(N + 1) * 128 * 2);   // +1: zero row
    u16*   vbuf     = (u16*)take((size_t)N * 128 * 2);         // layer-3 agg output
    u16*   Wt1      = (u16*)take((size_t)128 * 64 * 2);
    u16*   Wt2      = (u16*)take((size_t)128 * 128 * 2);
    float* WhF      = (float*)take((size_t)128 * 8 * 4);       // W3 @ Wh
    float* bhF      = (float*)take(8 * 4);                     // b3 @ Wh + bh

    int nblk  = (N + 255) / 256;
    int fgrid = (N + 15) / 16;
    int total8 = N * 64 / 8;
    int prep_threads = E + N + total8 + 25608 + 40;

    hipMemsetAsync(deg, 0, (size_t)N * 4, stream);

    deg_kernel<<<(E + 2047) / 2048, 256, 0, stream>>>(edst, deg, rank, E);
    scan_blocksum<<<nblk, 256, 0, stream>>>(deg, bsum, dinv, N);
    scan_offsets<<<1, 256, 0, stream>>>(bsum, boff, nblk);
    scan_rowptr<<<nblk, 256, 0, stream>>>(deg, boff, row_ptr, N);
    prep_kernel<<<(prep_threads + 255) / 256, 256, 0, stream>>>(
        esrc, edst, rank, row_ptr, deg, csr_src, x, dinv,
        (unsigned*)x16, (unsigned*)h16a, (unsigned*)h16b,
        W1, W2, W3, Wh, b3, bh, Wt1, Wt2, WhF, bhF, E, N, total8);

    // Layers 1,2 fused agg+GEMM (Agg(x)@W == Agg(x@W) at layer 1); layer 3 = pure gather
    agg_gemm<64,  true, true><<<fgrid, 256, 0, stream>>>(x16,  Wt1, b1, h16a, row_ptr, csr_src, dinv, N);
    agg_gemm<128, true, true><<<fgrid, 256, 0, stream>>>(h16a, Wt2, b2, h16b, row_ptr, csr_src, dinv, N);
    agg_only<<<fgrid, 256, 0, stream>>>(h16b, vbuf, row_ptr, csr_src, dinv, N);

    // Pool (binary-searched ranges) + folded head
    pool_part<<<G * PSPLIT, 256, 0, stream>>>(vbuf, batch, part, N);
    pool_head<<<G, 128, 0, stream>>>(part, batch, WhF, bhF, (float*)d_out, N);
}